// Round 2
// baseline (164.477 us; speedup 1.0000x reference)
//
#include <hip/hip_runtime.h>
#include <hip/hip_bf16.h>

#define BATCH 32
#define WW 900
#define CCH 256
#define PVAL 450
#define NCHUNK 64
#define NCHUNKS 15   // 15*64 = 960 >= 900

typedef __bf16 bf16x8 __attribute__((ext_vector_type(8)));
typedef float f32x4 __attribute__((ext_vector_type(4)));

// ---------------- norm pass 1: partial sums of squares ----------------
// grid = 256 blocks: which(2) x b(32) x seg(4); block = 256 threads (c)
// ws layout: sums[64][4][256] floats, then inv[64][256] at float offset 65536
__global__ void nc_norm_partial(const float* __restrict__ x1,
                                const float* __restrict__ x2,
                                float* __restrict__ sums) {
    int blk = blockIdx.x;
    int seg = blk & 3;
    int b = (blk >> 2) & 31;
    int which = blk >> 7;
    const float* x = which ? x2 : x1;
    int c = threadIdx.x;
    const float* p = x + ((size_t)b * WW + seg * 225) * CCH + c;
    float s = 0.f;
    #pragma unroll 8
    for (int w = 0; w < 225; ++w) {
        float v = p[(size_t)w * CCH];
        s = fmaf(v, v, s);
    }
    sums[(((which << 5) | b) * 4 + seg) * CCH + c] = s;
}

// ---------------- norm pass 2: inv = rsqrt(max(sum, eps)) ----------------
__global__ void nc_norm_finalize(float* __restrict__ ws) {
    int i = blockIdx.x * 256 + threadIdx.x;   // [0, 64*256)
    int c = i & 255;
    int wb = i >> 8;                          // which*32 + b
    const float* s = ws + (size_t)wb * 4 * CCH + c;
    float t = (s[0] + s[CCH]) + (s[2 * CCH] + s[3 * CCH]);
    ws[65536 + i] = rsqrtf(fmaxf(t, 1e-12f));
}

// ---------------- main: per-batch strip GEMM + fused diagonal reduction ----------------
// grid = 256: b = blockIdx&31, strip = blockIdx>>5, block tile 128 x 900(padded 960)
// A (128 rows) in registers per wave; B double-buffered 64-row chunks in LDS.
__global__ __launch_bounds__(256, 1)
void nc_corr(const float* __restrict__ x1,
             const float* __restrict__ x2,
             const float* __restrict__ ws,
             float* __restrict__ out) {
    __shared__ __bf16 Bbuf[2][NCHUNK * CCH];   // 2 x 32 KB
    __shared__ float partial[WW];              // 3.6 KB

    const int tid = threadIdx.x;
    const int b = blockIdx.x & 31;
    const int strip = blockIdx.x >> 5;
    const int m0 = strip * 128;

    const float* __restrict__ inv1 = ws + 65536 + b * CCH;
    const float* __restrict__ inv2 = ws + 65536 + (BATCH + b) * CCH;
    const float* __restrict__ x1b = x1 + (size_t)b * WW * CCH;
    const float* __restrict__ x2b = x2 + (size_t)b * WW * CCH;

    for (int i = tid; i < WW; i += 256) partial[i] = 0.f;

    const int lane = tid & 63;
    const int wave = tid >> 6;
    const int wm = wave >> 1;      // 0..1 : which 64-row half of A strip
    const int wn = wave & 1;       // 0..1 : which 32-col half of B chunk
    const int fr = lane & 15;
    const int fq = lane >> 4;

    // ---- A fragments: direct global -> registers (normalized, bf16) ----
    // af[mt][kk] holds A row (m0 + wm*64 + mt*16 + fr), cols kk*32+fq*8 .. +8
    bf16x8 af[4][8];
    #pragma unroll
    for (int mt = 0; mt < 4; ++mt) {
        const int row = m0 + wm * 64 + mt * 16 + fr;
        const float* src = x1b + (size_t)row * CCH;
        #pragma unroll
        for (int kk = 0; kk < 8; ++kk) {
            const int k0 = kk * 32 + fq * 8;
            bf16x8 v;
            if (row < WW) {
                float4 f0 = *(const float4*)(src + k0);
                float4 f1 = *(const float4*)(src + k0 + 4);
                float4 i0 = *(const float4*)(inv1 + k0);
                float4 i1 = *(const float4*)(inv1 + k0 + 4);
                v[0] = (__bf16)(f0.x * i0.x); v[1] = (__bf16)(f0.y * i0.y);
                v[2] = (__bf16)(f0.z * i0.z); v[3] = (__bf16)(f0.w * i0.w);
                v[4] = (__bf16)(f1.x * i1.x); v[5] = (__bf16)(f1.y * i1.y);
                v[6] = (__bf16)(f1.z * i1.z); v[7] = (__bf16)(f1.w * i1.w);
            } else {
                #pragma unroll
                for (int e = 0; e < 8; ++e) v[e] = (__bf16)0.f;
            }
            af[mt][kk] = v;
        }
    }

    // ---- B staging: fixed granule per thread, inv2 hoisted to registers ----
    const int sg = tid & 31;   // 8-float granule within a row
    const int sr = tid >> 5;   // base row 0..7 (rows sr + 8k)
    float iv[8];
    #pragma unroll
    for (int e = 0; e < 8; ++e) iv[e] = inv2[sg * 8 + e];

    float4 st[16];   // in-flight staged fp32 (8 rows x 32B)

    auto loadB = [&](int chunk) {
        const int n0 = chunk * NCHUNK;
        #pragma unroll
        for (int k = 0; k < 8; ++k) {
            const int row = n0 + sr + 8 * k;
            if (row < WW) {
                const float* s = x2b + (size_t)row * CCH + sg * 8;
                st[2 * k]     = *(const float4*)s;
                st[2 * k + 1] = *(const float4*)(s + 4);
            } else {
                st[2 * k]     = make_float4(0.f, 0.f, 0.f, 0.f);
                st[2 * k + 1] = make_float4(0.f, 0.f, 0.f, 0.f);
            }
        }
    };
    auto writeB = [&](int buf) {
        #pragma unroll
        for (int k = 0; k < 8; ++k) {
            const int row = sr + 8 * k;
            bf16x8 v;
            v[0] = (__bf16)(st[2*k].x   * iv[0]); v[1] = (__bf16)(st[2*k].y   * iv[1]);
            v[2] = (__bf16)(st[2*k].z   * iv[2]); v[3] = (__bf16)(st[2*k].w   * iv[3]);
            v[4] = (__bf16)(st[2*k+1].x * iv[4]); v[5] = (__bf16)(st[2*k+1].y * iv[5]);
            v[6] = (__bf16)(st[2*k+1].z * iv[6]); v[7] = (__bf16)(st[2*k+1].w * iv[7]);
            *(bf16x8*)(&Bbuf[buf][row * CCH + ((sg ^ (row & 7)) << 3)]) = v;
        }
    };

    loadB(0);
    writeB(0);
    __syncthreads();   // B chunk 0 staged, partial zeroed

    int cur = 0;
    for (int chunk = 0; chunk < NCHUNKS; ++chunk) {
        // issue next chunk's global loads early (hide under MFMA+epilogue)
        if (chunk + 1 < NCHUNKS) loadB(chunk + 1);

        f32x4 acc[4][2];
        #pragma unroll
        for (int mt = 0; mt < 4; ++mt)
            #pragma unroll
            for (int nt = 0; nt < 2; ++nt)
                acc[mt][nt] = (f32x4){0.f, 0.f, 0.f, 0.f};

        #pragma unroll
        for (int kk = 0; kk < 8; ++kk) {
            bf16x8 bfr[2];
            #pragma unroll
            for (int nt = 0; nt < 2; ++nt) {
                const int row = wn * 32 + nt * 16 + fr;
                const int gr = (kk * 4 + fq) ^ (row & 7);
                bfr[nt] = *(const bf16x8*)(&Bbuf[cur][row * CCH + (gr << 3)]);
            }
            #pragma unroll
            for (int mt = 0; mt < 4; ++mt)
                #pragma unroll
                for (int nt = 0; nt < 2; ++nt)
                    acc[mt][nt] = __builtin_amdgcn_mfma_f32_16x16x32_bf16(
                        af[mt][kk], bfr[nt], acc[mt][nt], 0, 0, 0);
        }

        // Epilogue: G[m,i] -> j = (m - i - 450) mod 900; combine equal-diagonal tiles
        const int base_mi = (m0 + wm * 64) - (chunk * NCHUNK + wn * 32) + 4 * fq - fr - PVAL;
        #pragma unroll
        for (int d = -1; d <= 3; ++d) {
            f32x4 comb = (f32x4){0.f, 0.f, 0.f, 0.f};
            #pragma unroll
            for (int mt = 0; mt < 4; ++mt) {
                const int nt = mt - d;
                if (nt >= 0 && nt < 2) comb += acc[mt][nt];
            }
            int j0 = base_mi + 16 * d;
            j0 %= WW;
            if (j0 < 0) j0 += WW;
            #pragma unroll
            for (int r = 0; r < 4; ++r) {
                int j = j0 + r;
                if (j >= WW) j -= WW;
                atomicAdd(&partial[j], comb[r]);
            }
        }

        // convert + write next chunk into the other buffer, then single barrier
        if (chunk + 1 < NCHUNKS) writeB(cur ^ 1);
        __syncthreads();
        cur ^= 1;
    }

    for (int i = tid; i < WW; i += 256)
        atomicAdd(&out[(size_t)b * WW + i], partial[i]);
}

extern "C" void kernel_launch(void* const* d_in, const int* in_sizes, int n_in,
                              void* d_out, int out_size, void* d_ws, size_t ws_size,
                              hipStream_t stream) {
    const float* x1 = (const float*)d_in[0];
    const float* x2 = (const float*)d_in[1];
    float* out = (float*)d_out;
    float* ws = (float*)d_ws;   // needs 320 KB: 256 KB partial sums + 64 KB inv

    hipMemsetAsync(d_out, 0, (size_t)out_size * sizeof(float), stream);
    nc_norm_partial<<<256, 256, 0, stream>>>(x1, x2, ws);
    nc_norm_finalize<<<64, 256, 0, stream>>>(ws);
    nc_corr<<<256, 256, 0, stream>>>(x1, x2, ws, out);
}